// Round 1
// baseline (1377.351 us; speedup 1.0000x reference)
//
#include <hip/hip_runtime.h>
#include <hip/hip_bf16.h>
#include <math.h>

#define NN_F_IN   512
#define NN_HID    256
#define NN_HEADS  8
#define NN_FH     32
#define NN_NCLASS 40
#define TAU_F     0.5f
#define LAMDA_F   0.5f

static __device__ __forceinline__ float lrelu02(float x) { return x >= 0.f ? x : 0.2f * x; }
static __device__ __forceinline__ float elu1(float x)    { return x > 0.f ? x : expm1f(x); }

// ---------------------------------------------------------------------------
// Dense: H[n][o] = sum_f X[n][f] * W[f][o].  block = outdim threads, 8 nodes/block.
// ---------------------------------------------------------------------------
__global__ void fc_kernel(const float* __restrict__ X, const float* __restrict__ W,
                          float* __restrict__ H, int n, int fin, int outdim) {
    __shared__ __align__(16) float xs[8 * 512];
    int n0 = blockIdx.x * 8;
    int o  = threadIdx.x;
    int total = 8 * fin;
    for (int idx = threadIdx.x; idx < total; idx += blockDim.x) {
        int nb = idx / fin, f = idx - nb * fin;
        int nn = n0 + nb;
        xs[nb * fin + f] = (nn < n) ? X[(size_t)nn * fin + f] : 0.f;
    }
    __syncthreads();
    float acc[8] = {0.f, 0.f, 0.f, 0.f, 0.f, 0.f, 0.f, 0.f};
    for (int f4 = 0; f4 < fin; f4 += 4) {
        float4 xv[8];
#pragma unroll
        for (int nb = 0; nb < 8; ++nb) xv[nb] = *(const float4*)&xs[nb * fin + f4];
#pragma unroll
        for (int j = 0; j < 4; ++j) {
            float w = W[(size_t)(f4 + j) * outdim + o];
#pragma unroll
            for (int nb = 0; nb < 8; ++nb) {
                float xj = (j == 0) ? xv[nb].x : (j == 1) ? xv[nb].y : (j == 2) ? xv[nb].z : xv[nb].w;
                acc[nb] += xj * w;
            }
        }
    }
#pragma unroll
    for (int nb = 0; nb < 8; ++nb) {
        int nn = n0 + nb;
        if (nn < n) H[(size_t)nn * outdim + o] = acc[nb];
    }
}

// ---------------------------------------------------------------------------
// es[n][h] = <h[n][h][:], a_s[h][:]> ; ed likewise. one thread per (n,h).
// ---------------------------------------------------------------------------
__global__ void attn_kernel(const float* __restrict__ Hm, const float* __restrict__ As,
                            const float* __restrict__ Ad, float* __restrict__ es,
                            float* __restrict__ ed, int n, int df) {
    int idx = blockIdx.x * blockDim.x + threadIdx.x;
    if (idx >= n * NN_HEADS) return;
    int nn = idx / NN_HEADS, hh = idx - nn * NN_HEADS;
    const float* hp = Hm + (size_t)nn * NN_HEADS * df + hh * df;
    const float* ap = As + hh * df;
    const float* bp = Ad + hh * df;
    float s1 = 0.f, s2 = 0.f;
    for (int d = 0; d < df; d += 4) {
        float4 hv = *(const float4*)(hp + d);
        float4 av = *(const float4*)(ap + d);
        float4 bv = *(const float4*)(bp + d);
        s1 += hv.x * av.x + hv.y * av.y + hv.z * av.z + hv.w * av.w;
        s2 += hv.x * bv.x + hv.y * bv.y + hv.z * bv.z + hv.w * bv.w;
    }
    es[idx] = s1;
    ed[idx] = s2;
}

// ---------------------------------------------------------------------------
// CSR build (per launch; deterministic work)
// ---------------------------------------------------------------------------
__global__ void count_kernel(const int* __restrict__ dst, int* __restrict__ counts, int E) {
    int e = blockIdx.x * blockDim.x + threadIdx.x;
    if (e < E) atomicAdd(&counts[dst[e]], 1);
}

__global__ void scan_kernel(const int* __restrict__ counts, int* __restrict__ row_start, int n) {
    __shared__ int s[1024];
    int t  = threadIdx.x;
    int ch = (n + 1023) / 1024;
    int lo = t * ch;
    int sum = 0;
    for (int j = 0; j < ch; ++j) {
        int i = lo + j;
        if (i < n) sum += counts[i];
    }
    s[t] = sum;
    __syncthreads();
    for (int off = 1; off < 1024; off <<= 1) {
        int v = 0;
        if (t >= off) v = s[t - off];
        __syncthreads();
        s[t] += v;
        __syncthreads();
    }
    int run = (t == 0) ? 0 : s[t - 1];
    for (int j = 0; j < ch; ++j) {
        int i = lo + j;
        if (i < n) {
            row_start[i] = run;
            run += counts[i];
        }
    }
    if (t == 1023) row_start[n] = s[1023];
}

__global__ void cursor_init(const int* __restrict__ rs, int* __restrict__ cursor, int n) {
    int i = blockIdx.x * blockDim.x + threadIdx.x;
    if (i < n) cursor[i] = rs[i];
}

__global__ void scatter_kernel(const int* __restrict__ src, const int* __restrict__ dst,
                               int* __restrict__ cursor, int* __restrict__ csr_src, int E) {
    int e = blockIdx.x * blockDim.x + threadIdx.x;
    if (e < E) {
        int d   = dst[e];
        int pos = atomicAdd(&cursor[d], 1);
        csr_src[pos] = src[e];
    }
}

// ---------------------------------------------------------------------------
// Per-dst edge softmax + aggregation (hidden layers, OUT=256).
// e is bounded (|e|<~3) so exp without max-shift is numerically identical.
// ---------------------------------------------------------------------------
__global__ void gather_hidden(const float* __restrict__ Hm, const float* __restrict__ es,
                              const float* __restrict__ ed, const int* __restrict__ csr_src,
                              const int* __restrict__ row_start, const float* __restrict__ last,
                              float* __restrict__ out, int n, float beta) {
    int nn = blockIdx.x;
    __shared__ float edn[NN_HEADS];
    __shared__ float zs[NN_HEADS];
    __shared__ float zinv[NN_HEADS];
    int t = threadIdx.x;
    if (t < NN_HEADS) {
        edn[t] = ed[nn * NN_HEADS + t];
        zs[t]  = 0.f;
    }
    __syncthreads();
    int s0 = row_start[nn], s1 = row_start[nn + 1];
    int work = (s1 - s0) * NN_HEADS;
    for (int idx = t; idx < work; idx += blockDim.x) {
        int e  = s0 + (idx >> 3);
        int hh = idx & 7;
        int sv = csr_src[e];
        float ev = lrelu02(es[sv * NN_HEADS + hh] + edn[hh]);
        atomicAdd(&zs[hh], expf(ev));
    }
    __syncthreads();
    if (t < NN_HEADS) zinv[t] = 1.f / zs[t];
    __syncthreads();
    int   hh  = t >> 5;  // FH = 32
    float edh = edn[hh];
    float zi  = zinv[hh];
    float acc = 0.f;
    for (int e = s0; e < s1; ++e) {
        int sv = csr_src[e];
        float w = expf(lrelu02(es[sv * NN_HEADS + hh] + edh)) * zi;
        acc += w * Hm[(size_t)sv * NN_HID + t];
    }
    float v = elu1(acc);
    if (beta >= 0.f) v = beta * last[(size_t)nn * NN_HID + t] + (1.f - beta) * v;
    out[(size_t)nn * NN_HID + t] = v;
}

// ---------------------------------------------------------------------------
// Final layer: aggregate [N,H,C], mean over heads, log_softmax over C -> d_out
// ---------------------------------------------------------------------------
__global__ void gather_final(const float* __restrict__ Hm, const float* __restrict__ es,
                             const float* __restrict__ ed, const int* __restrict__ csr_src,
                             const int* __restrict__ row_start, float* __restrict__ dout, int n) {
    int nn = blockIdx.x;
    __shared__ float edn[NN_HEADS];
    __shared__ float zs[NN_HEADS];
    __shared__ float zinv[NN_HEADS];
    __shared__ float accs[NN_HEADS * NN_NCLASS];
    int t = threadIdx.x;  // 0..319
    if (t < NN_HEADS) {
        edn[t] = ed[nn * NN_HEADS + t];
        zs[t]  = 0.f;
    }
    __syncthreads();
    int s0 = row_start[nn], s1 = row_start[nn + 1];
    int work = (s1 - s0) * NN_HEADS;
    for (int idx = t; idx < work; idx += blockDim.x) {
        int e  = s0 + (idx >> 3);
        int hh = idx & 7;
        int sv = csr_src[e];
        atomicAdd(&zs[hh], expf(lrelu02(es[sv * NN_HEADS + hh] + edn[hh])));
    }
    __syncthreads();
    if (t < NN_HEADS) zinv[t] = 1.f / zs[t];
    __syncthreads();
    int   hh  = t / NN_NCLASS;
    float edh = edn[hh];
    float zi  = zinv[hh];
    float acc = 0.f;
    for (int e = s0; e < s1; ++e) {
        int sv = csr_src[e];
        float w = expf(lrelu02(es[sv * NN_HEADS + hh] + edh)) * zi;
        acc += w * Hm[(size_t)sv * (NN_HEADS * NN_NCLASS) + t];
    }
    accs[t] = acc;
    __syncthreads();
    if (t < 64) {
        float v = -INFINITY;
        if (t < NN_NCLASS) {
            float sacc = 0.f;
#pragma unroll
            for (int h2 = 0; h2 < NN_HEADS; ++h2) sacc += accs[h2 * NN_NCLASS + t];
            v = sacc * (1.f / NN_HEADS);
        }
        float mx = v;
#pragma unroll
        for (int o = 1; o < 64; o <<= 1) mx = fmaxf(mx, __shfl_xor(mx, o, 64));
        float ex = (t < NN_NCLASS) ? expf(v - mx) : 0.f;
        float se = ex;
#pragma unroll
        for (int o = 1; o < 64; o <<= 1) se += __shfl_xor(se, o, 64);
        if (t < NN_NCLASS) dout[(size_t)nn * NN_NCLASS + t] = (v - mx) - logf(se);
    }
}

// ---------------------------------------------------------------------------
// Row-normalize + analytic diagonal d_i = exp(||zn_i||^2 / tau)
// ---------------------------------------------------------------------------
__global__ void rownorm_kernel(const float* __restrict__ z, float* __restrict__ zn,
                               float* __restrict__ dvec, int n) {
    int nn = blockIdx.x;
    int t  = threadIdx.x;  // 256
    float v  = z[(size_t)nn * NN_HID + t];
    float sq = v * v;
#pragma unroll
    for (int o = 1; o < 64; o <<= 1) sq += __shfl_xor(sq, o, 64);
    __shared__ float ws[4];
    if ((t & 63) == 0) ws[t >> 6] = sq;
    __syncthreads();
    float s = ws[0] + ws[1] + ws[2] + ws[3];
    float m = fmaxf(sqrtf(s), 1e-12f);
    zn[(size_t)nn * NN_HID + t] = v / m;
    if (t == 0) dvec[nn] = expf((s / (m * m)) * (1.f / TAU_F));
}

// ---------------------------------------------------------------------------
// R[i] = sum_j exp(<zn_i, zn_j>/tau)  — fp32 SGEMM-style 128x128 tile, 8x8 micro
// ---------------------------------------------------------------------------
#define GT   128
#define KS   16
#define LSTR 132

__global__ __launch_bounds__(256) void gram_kernel(const float* __restrict__ zn,
                                                   float* __restrict__ R, int n) {
    __shared__ __align__(16) float As[KS * LSTR];
    __shared__ __align__(16) float Bs[KS * LSTR];
    int i0 = blockIdx.y * GT;
    int j0 = blockIdx.x * GT;
    int t  = threadIdx.x;
    int tx = t & 15, ty = t >> 4;
    float acc[8][8];
#pragma unroll
    for (int r = 0; r < 8; ++r)
#pragma unroll
        for (int c = 0; c < 8; ++c) acc[r][c] = 0.f;

    for (int kk = 0; kk < NN_HID; kk += KS) {
#pragma unroll
        for (int p = 0; p < 2; ++p) {
            int l   = t + p * 256;  // 0..511
            int row = l >> 2;
            int c4  = l & 3;
            int gi  = i0 + row;
            float4 va = (gi < n) ? *(const float4*)&zn[(size_t)gi * NN_HID + kk + c4 * 4]
                                 : make_float4(0.f, 0.f, 0.f, 0.f);
            As[(c4 * 4 + 0) * LSTR + row] = va.x;
            As[(c4 * 4 + 1) * LSTR + row] = va.y;
            As[(c4 * 4 + 2) * LSTR + row] = va.z;
            As[(c4 * 4 + 3) * LSTR + row] = va.w;
            int gj = j0 + row;
            float4 vb = (gj < n) ? *(const float4*)&zn[(size_t)gj * NN_HID + kk + c4 * 4]
                                 : make_float4(0.f, 0.f, 0.f, 0.f);
            Bs[(c4 * 4 + 0) * LSTR + row] = vb.x;
            Bs[(c4 * 4 + 1) * LSTR + row] = vb.y;
            Bs[(c4 * 4 + 2) * LSTR + row] = vb.z;
            Bs[(c4 * 4 + 3) * LSTR + row] = vb.w;
        }
        __syncthreads();
#pragma unroll
        for (int k = 0; k < KS; ++k) {
            float a[8], b[8];
            float4 a0 = *(const float4*)&As[k * LSTR + ty * 4];
            float4 a1 = *(const float4*)&As[k * LSTR + ty * 4 + 64];
            float4 b0 = *(const float4*)&Bs[k * LSTR + tx * 4];
            float4 b1 = *(const float4*)&Bs[k * LSTR + tx * 4 + 64];
            a[0] = a0.x; a[1] = a0.y; a[2] = a0.z; a[3] = a0.w;
            a[4] = a1.x; a[5] = a1.y; a[6] = a1.z; a[7] = a1.w;
            b[0] = b0.x; b[1] = b0.y; b[2] = b0.z; b[3] = b0.w;
            b[4] = b1.x; b[5] = b1.y; b[6] = b1.z; b[7] = b1.w;
#pragma unroll
            for (int r = 0; r < 8; ++r)
#pragma unroll
                for (int c = 0; c < 8; ++c) acc[r][c] += a[r] * b[c];
        }
        __syncthreads();
    }
    // epilogue: exp + row sums, reduce across tx lanes, atomic into R
#pragma unroll
    for (int r = 0; r < 8; ++r) {
        float rsum = 0.f;
#pragma unroll
        for (int c = 0; c < 8; ++c) {
            int gj = j0 + tx * 4 + (c & 3) + (c >> 2) * 64;
            if (gj < n) rsum += expf(acc[r][c] * (1.f / TAU_F));
        }
#pragma unroll
        for (int o = 1; o < 16; o <<= 1) rsum += __shfl_xor(rsum, o, 64);
        if (tx == 0) {
            int gi = i0 + ty * 4 + (r & 3) + (r >> 2) * 64;
            if (gi < n) atomicAdd(&R[gi], rsum);
        }
    }
}

__global__ void loss_kernel(const float* __restrict__ R, const float* __restrict__ dvec,
                            float* __restrict__ out_loss, int n) {
    __shared__ float s[1024];
    int t = threadIdx.x;
    float sum = 0.f;
    for (int i = t; i < n; i += 1024) {
        float d   = dvec[i];
        float off = R[i] - d;
        sum += -logf(d / (off + off));
    }
    s[t] = sum;
    __syncthreads();
    for (int o = 512; o > 0; o >>= 1) {
        if (t < o) s[t] += s[t + o];
        __syncthreads();
    }
    if (t == 0) *out_loss = s[0] / n;
}

// ---------------------------------------------------------------------------
extern "C" void kernel_launch(void* const* d_in, const int* in_sizes, int n_in,
                              void* d_out, int out_size, void* d_ws, size_t ws_size,
                              hipStream_t stream) {
    const float* x   = (const float*)d_in[0];
    const int*   src = (const int*)d_in[1];
    const int*   dst = (const int*)d_in[2];
    const float* W0  = (const float*)d_in[3];
    const float* a0s = (const float*)d_in[4];
    const float* a0d = (const float*)d_in[5];
    const float* W1  = (const float*)d_in[6];
    const float* a1s = (const float*)d_in[7];
    const float* a1d = (const float*)d_in[8];
    const float* W2  = (const float*)d_in[9];
    const float* a2s = (const float*)d_in[10];
    const float* a2d = (const float*)d_in[11];
    const float* Wout= (const float*)d_in[12];
    const float* aos = (const float*)d_in[13];
    const float* aod = (const float*)d_in[14];

    int N = in_sizes[0] / NN_F_IN;
    int E = in_sizes[1];
    float* out = (float*)d_out;

    char*  ws  = (char*)d_ws;
    size_t off = 0;
    auto alloc = [&](size_t bytes) -> void* {
        void* p = ws + off;
        off += bytes;
        off = (off + 255) & ~(size_t)255;
        return p;
    };
    float* Bh     = (float*)alloc((size_t)N * NN_HEADS * NN_NCLASS * 4);  // 320 cols, also holds zn
    float* Bl     = (float*)alloc((size_t)N * NN_HID * 4);
    float* Bc     = (float*)alloc((size_t)N * NN_HID * 4);
    float* es     = (float*)alloc((size_t)N * NN_HEADS * 4);
    float* ed     = (float*)alloc((size_t)N * NN_HEADS * 4);
    float* Rrow   = (float*)alloc((size_t)N * 4);
    float* dvec   = (float*)alloc((size_t)N * 4);
    int*   counts = (int*)alloc((size_t)N * 4);
    int*   rs     = (int*)alloc((size_t)(N + 1) * 4);
    int*   cursor = (int*)alloc((size_t)N * 4);
    int*   csr    = (int*)alloc((size_t)E * 4);

    // ---- CSR build (used by all 4 GAT layers)
    hipMemsetAsync(counts, 0, (size_t)N * 4, stream);
    count_kernel<<<(E + 255) / 256, 256, 0, stream>>>(dst, counts, E);
    scan_kernel<<<1, 1024, 0, stream>>>(counts, rs, N);
    cursor_init<<<(N + 255) / 256, 256, 0, stream>>>(rs, cursor, N);
    scatter_kernel<<<(E + 255) / 256, 256, 0, stream>>>(src, dst, cursor, csr, E);

    int fcGrid = (N + 7) / 8;
    int atGrid = (N * NN_HEADS + 255) / 256;

    // ---- layer 0: x -> Bl
    fc_kernel<<<fcGrid, NN_HID, 0, stream>>>(x, W0, Bh, N, NN_F_IN, NN_HID);
    attn_kernel<<<atGrid, 256, 0, stream>>>(Bh, a0s, a0d, es, ed, N, NN_FH);
    gather_hidden<<<N, 256, 0, stream>>>(Bh, es, ed, csr, rs, nullptr, Bl, N, -1.f);

    // ---- layer 1: Bl -> Bc  (beta = 0.5/3)
    fc_kernel<<<fcGrid, NN_HID, 0, stream>>>(Bl, W1, Bh, N, NN_HID, NN_HID);
    attn_kernel<<<atGrid, 256, 0, stream>>>(Bh, a1s, a1d, es, ed, N, NN_FH);
    gather_hidden<<<N, 256, 0, stream>>>(Bh, es, ed, csr, rs, Bl, Bc, N, LAMDA_F / 3.f);

    // ---- layer 2: Bc -> Bl  (beta = 0.5/4), then bind_loss on Bl
    fc_kernel<<<fcGrid, NN_HID, 0, stream>>>(Bc, W2, Bh, N, NN_HID, NN_HID);
    attn_kernel<<<atGrid, 256, 0, stream>>>(Bh, a2s, a2d, es, ed, N, NN_FH);
    gather_hidden<<<N, 256, 0, stream>>>(Bh, es, ed, csr, rs, Bc, Bl, N, LAMDA_F / 4.f);

    // ---- bind_loss(Bl): zn in Bh, rowsums in Rrow, loss -> out[N*NCLASS]
    rownorm_kernel<<<N, 256, 0, stream>>>(Bl, Bh, dvec, N);
    hipMemsetAsync(Rrow, 0, (size_t)N * 4, stream);
    dim3 gg((N + GT - 1) / GT, (N + GT - 1) / GT);
    gram_kernel<<<gg, 256, 0, stream>>>(Bh, Rrow, N);
    loss_kernel<<<1, 1024, 0, stream>>>(Rrow, dvec, out + (size_t)N * NN_NCLASS, N);

    // ---- output layer: Bl -> logits (overwrites Bh after gram is done)
    fc_kernel<<<fcGrid, NN_HEADS * NN_NCLASS, 0, stream>>>(Bl, Wout, Bh, N, NN_HID, NN_HEADS * NN_NCLASS);
    attn_kernel<<<atGrid, 256, 0, stream>>>(Bh, aos, aod, es, ed, N, NN_NCLASS);
    gather_final<<<N, NN_HEADS * NN_NCLASS, 0, stream>>>(Bh, es, ed, csr, rs, out, N);
}

// Round 2
// 933.536 us; speedup vs baseline: 1.4754x; 1.4754x over previous
//
#include <hip/hip_runtime.h>
#include <hip/hip_bf16.h>
#include <math.h>

#define NN_F_IN   512
#define NN_HID    256
#define NN_HEADS  8
#define NN_FH     32
#define NN_NCLASS 40
#define TAU_F     0.5f
#define LAMDA_F   0.5f

typedef __attribute__((ext_vector_type(8))) short bf16x8;
typedef __attribute__((ext_vector_type(4))) float f32x4;

static __device__ __forceinline__ float lrelu02(float x) { return x >= 0.f ? x : 0.2f * x; }
static __device__ __forceinline__ float elu1(float x)    { return x > 0.f ? x : expm1f(x); }

// ---------------------------------------------------------------------------
// Dense: H[n][o] = sum_f X[n][f] * W[f][o].  block = outdim threads, 8 nodes/block.
// ---------------------------------------------------------------------------
__global__ void fc_kernel(const float* __restrict__ X, const float* __restrict__ W,
                          float* __restrict__ H, int n, int fin, int outdim) {
    __shared__ __align__(16) float xs[8 * 512];
    int n0 = blockIdx.x * 8;
    int o  = threadIdx.x;
    int total = 8 * fin;
    for (int idx = threadIdx.x; idx < total; idx += blockDim.x) {
        int nb = idx / fin, f = idx - nb * fin;
        int nn = n0 + nb;
        xs[nb * fin + f] = (nn < n) ? X[(size_t)nn * fin + f] : 0.f;
    }
    __syncthreads();
    float acc[8] = {0.f, 0.f, 0.f, 0.f, 0.f, 0.f, 0.f, 0.f};
    for (int f4 = 0; f4 < fin; f4 += 4) {
        float4 xv[8];
#pragma unroll
        for (int nb = 0; nb < 8; ++nb) xv[nb] = *(const float4*)&xs[nb * fin + f4];
#pragma unroll
        for (int j = 0; j < 4; ++j) {
            float w = W[(size_t)(f4 + j) * outdim + o];
#pragma unroll
            for (int nb = 0; nb < 8; ++nb) {
                float xj = (j == 0) ? xv[nb].x : (j == 1) ? xv[nb].y : (j == 2) ? xv[nb].z : xv[nb].w;
                acc[nb] += xj * w;
            }
        }
    }
#pragma unroll
    for (int nb = 0; nb < 8; ++nb) {
        int nn = n0 + nb;
        if (nn < n) H[(size_t)nn * outdim + o] = acc[nb];
    }
}

// ---------------------------------------------------------------------------
// es[n][h] = <h[n][h][:], a_s[h][:]> ; ed likewise. one thread per (n,h).
// ---------------------------------------------------------------------------
__global__ void attn_kernel(const float* __restrict__ Hm, const float* __restrict__ As,
                            const float* __restrict__ Ad, float* __restrict__ es,
                            float* __restrict__ ed, int n, int df) {
    int idx = blockIdx.x * blockDim.x + threadIdx.x;
    if (idx >= n * NN_HEADS) return;
    int nn = idx / NN_HEADS, hh = idx - nn * NN_HEADS;
    const float* hp = Hm + (size_t)nn * NN_HEADS * df + hh * df;
    const float* ap = As + hh * df;
    const float* bp = Ad + hh * df;
    float s1 = 0.f, s2 = 0.f;
    for (int d = 0; d < df; d += 4) {
        float4 hv = *(const float4*)(hp + d);
        float4 av = *(const float4*)(ap + d);
        float4 bv = *(const float4*)(bp + d);
        s1 += hv.x * av.x + hv.y * av.y + hv.z * av.z + hv.w * av.w;
        s2 += hv.x * bv.x + hv.y * bv.y + hv.z * bv.z + hv.w * bv.w;
    }
    es[idx] = s1;
    ed[idx] = s2;
}

// ---------------------------------------------------------------------------
// CSR build (per launch; deterministic work)
// ---------------------------------------------------------------------------
__global__ void count_kernel(const int* __restrict__ dst, int* __restrict__ counts, int E) {
    int e = blockIdx.x * blockDim.x + threadIdx.x;
    if (e < E) atomicAdd(&counts[dst[e]], 1);
}

__global__ void scan_kernel(const int* __restrict__ counts, int* __restrict__ row_start, int n) {
    __shared__ int s[1024];
    int t  = threadIdx.x;
    int ch = (n + 1023) / 1024;
    int lo = t * ch;
    int sum = 0;
    for (int j = 0; j < ch; ++j) {
        int i = lo + j;
        if (i < n) sum += counts[i];
    }
    s[t] = sum;
    __syncthreads();
    for (int off = 1; off < 1024; off <<= 1) {
        int v = 0;
        if (t >= off) v = s[t - off];
        __syncthreads();
        s[t] += v;
        __syncthreads();
    }
    int run = (t == 0) ? 0 : s[t - 1];
    for (int j = 0; j < ch; ++j) {
        int i = lo + j;
        if (i < n) {
            row_start[i] = run;
            run += counts[i];
        }
    }
    if (t == 1023) row_start[n] = s[1023];
}

__global__ void cursor_init(const int* __restrict__ rs, int* __restrict__ cursor, int n) {
    int i = blockIdx.x * blockDim.x + threadIdx.x;
    if (i < n) cursor[i] = rs[i];
}

__global__ void scatter_kernel(const int* __restrict__ src, const int* __restrict__ dst,
                               int* __restrict__ cursor, int* __restrict__ csr_src, int E) {
    int e = blockIdx.x * blockDim.x + threadIdx.x;
    if (e < E) {
        int d   = dst[e];
        int pos = atomicAdd(&cursor[d], 1);
        csr_src[pos] = src[e];
    }
}

// ---------------------------------------------------------------------------
// Per-dst edge softmax + aggregation (hidden layers, OUT=256).
// e is bounded (|e|<~3) so exp without max-shift is numerically identical.
// ---------------------------------------------------------------------------
__global__ void gather_hidden(const float* __restrict__ Hm, const float* __restrict__ es,
                              const float* __restrict__ ed, const int* __restrict__ csr_src,
                              const int* __restrict__ row_start, const float* __restrict__ last,
                              float* __restrict__ out, int n, float beta) {
    int nn = blockIdx.x;
    __shared__ float edn[NN_HEADS];
    __shared__ float zs[NN_HEADS];
    __shared__ float zinv[NN_HEADS];
    int t = threadIdx.x;
    if (t < NN_HEADS) {
        edn[t] = ed[nn * NN_HEADS + t];
        zs[t]  = 0.f;
    }
    __syncthreads();
    int s0 = row_start[nn], s1 = row_start[nn + 1];
    int work = (s1 - s0) * NN_HEADS;
    for (int idx = t; idx < work; idx += blockDim.x) {
        int e  = s0 + (idx >> 3);
        int hh = idx & 7;
        int sv = csr_src[e];
        float ev = lrelu02(es[sv * NN_HEADS + hh] + edn[hh]);
        atomicAdd(&zs[hh], expf(ev));
    }
    __syncthreads();
    if (t < NN_HEADS) zinv[t] = 1.f / zs[t];
    __syncthreads();
    int   hh  = t >> 5;  // FH = 32
    float edh = edn[hh];
    float zi  = zinv[hh];
    float acc = 0.f;
    for (int e = s0; e < s1; ++e) {
        int sv = csr_src[e];
        float w = expf(lrelu02(es[sv * NN_HEADS + hh] + edh)) * zi;
        acc += w * Hm[(size_t)sv * NN_HID + t];
    }
    float v = elu1(acc);
    if (beta >= 0.f) v = beta * last[(size_t)nn * NN_HID + t] + (1.f - beta) * v;
    out[(size_t)nn * NN_HID + t] = v;
}

// ---------------------------------------------------------------------------
// Final layer: aggregate [N,H,C], mean over heads, log_softmax over C -> d_out
// ---------------------------------------------------------------------------
__global__ void gather_final(const float* __restrict__ Hm, const float* __restrict__ es,
                             const float* __restrict__ ed, const int* __restrict__ csr_src,
                             const int* __restrict__ row_start, float* __restrict__ dout, int n) {
    int nn = blockIdx.x;
    __shared__ float edn[NN_HEADS];
    __shared__ float zs[NN_HEADS];
    __shared__ float zinv[NN_HEADS];
    __shared__ float accs[NN_HEADS * NN_NCLASS];
    int t = threadIdx.x;  // 0..319
    if (t < NN_HEADS) {
        edn[t] = ed[nn * NN_HEADS + t];
        zs[t]  = 0.f;
    }
    __syncthreads();
    int s0 = row_start[nn], s1 = row_start[nn + 1];
    int work = (s1 - s0) * NN_HEADS;
    for (int idx = t; idx < work; idx += blockDim.x) {
        int e  = s0 + (idx >> 3);
        int hh = idx & 7;
        int sv = csr_src[e];
        atomicAdd(&zs[hh], expf(lrelu02(es[sv * NN_HEADS + hh] + edn[hh])));
    }
    __syncthreads();
    if (t < NN_HEADS) zinv[t] = 1.f / zs[t];
    __syncthreads();
    int   hh  = t / NN_NCLASS;
    float edh = edn[hh];
    float zi  = zinv[hh];
    float acc = 0.f;
    for (int e = s0; e < s1; ++e) {
        int sv = csr_src[e];
        float w = expf(lrelu02(es[sv * NN_HEADS + hh] + edh)) * zi;
        acc += w * Hm[(size_t)sv * (NN_HEADS * NN_NCLASS) + t];
    }
    accs[t] = acc;
    __syncthreads();
    if (t < 64) {
        float v = -INFINITY;
        if (t < NN_NCLASS) {
            float sacc = 0.f;
#pragma unroll
            for (int h2 = 0; h2 < NN_HEADS; ++h2) sacc += accs[h2 * NN_NCLASS + t];
            v = sacc * (1.f / NN_HEADS);
        }
        float mx = v;
#pragma unroll
        for (int o = 1; o < 64; o <<= 1) mx = fmaxf(mx, __shfl_xor(mx, o, 64));
        float ex = (t < NN_NCLASS) ? expf(v - mx) : 0.f;
        float se = ex;
#pragma unroll
        for (int o = 1; o < 64; o <<= 1) se += __shfl_xor(se, o, 64);
        if (t < NN_NCLASS) dout[(size_t)nn * NN_NCLASS + t] = (v - mx) - logf(se);
    }
}

// ---------------------------------------------------------------------------
// Row-normalize + bf16 cast + analytic diagonal d_i = exp(||zn_i||^2 / tau)
// ---------------------------------------------------------------------------
__global__ void rownorm_kernel(const float* __restrict__ z, short* __restrict__ znb,
                               float* __restrict__ dvec, int n) {
    int nn = blockIdx.x;
    int t  = threadIdx.x;  // 256
    float v  = z[(size_t)nn * NN_HID + t];
    float sq = v * v;
#pragma unroll
    for (int o = 1; o < 64; o <<= 1) sq += __shfl_xor(sq, o, 64);
    __shared__ float ws[4];
    if ((t & 63) == 0) ws[t >> 6] = sq;
    __syncthreads();
    float s = ws[0] + ws[1] + ws[2] + ws[3];
    float m = fmaxf(sqrtf(s), 1e-12f);
    __hip_bfloat16 hb = __float2bfloat16(v / m);
    znb[(size_t)nn * NN_HID + t] = *reinterpret_cast<short*>(&hb);
    if (t == 0) dvec[nn] = expf((s / (m * m)) * (1.f / TAU_F));
}

// ---------------------------------------------------------------------------
// R[i] += sum_j exp(<zn_i,zn_j>/tau)  via bf16 MFMA, no LDS.
// Block: 128x128 tile, 4 waves 2x2, wave = 64x64 = 4x4 frags of 16x16x32.
// A and B frag loads are both 16B-contiguous zn rows (gram == B^T layout).
// ---------------------------------------------------------------------------
__global__ __launch_bounds__(256) void gram_mfma(const short* __restrict__ znb,
                                                 float* __restrict__ R, int n) {
    int i0   = blockIdx.y * 128;
    int j0   = blockIdx.x * 128;
    int t    = threadIdx.x;
    int lane = t & 63;
    int wid  = t >> 6;             // 0..3
    int wrow = wid >> 1, wcol = wid & 1;
    int l15  = lane & 15, lg = lane >> 4;

    const short* Abase = znb + (size_t)(i0 + wrow * 64 + l15) * NN_HID + lg * 8;
    const short* Bbase = znb + (size_t)(j0 + wcol * 64 + l15) * NN_HID + lg * 8;

    f32x4 acc[4][4];
#pragma unroll
    for (int m = 0; m < 4; ++m)
#pragma unroll
        for (int nn = 0; nn < 4; ++nn)
#pragma unroll
            for (int r = 0; r < 4; ++r) acc[m][nn][r] = 0.f;

#pragma unroll
    for (int kk = 0; kk < NN_HID; kk += 32) {
        bf16x8 a[4], b[4];
#pragma unroll
        for (int m = 0; m < 4; ++m)
            a[m] = *(const bf16x8*)(Abase + (size_t)m * 16 * NN_HID + kk);
#pragma unroll
        for (int nn = 0; nn < 4; ++nn)
            b[nn] = *(const bf16x8*)(Bbase + (size_t)nn * 16 * NN_HID + kk);
#pragma unroll
        for (int m = 0; m < 4; ++m)
#pragma unroll
            for (int nn = 0; nn < 4; ++nn)
                acc[m][nn] = __builtin_amdgcn_mfma_f32_16x16x32_bf16(a[m], b[nn], acc[m][nn], 0, 0, 0);
    }

    // epilogue: exp(2*acc), mask j<n, reduce over 16 col-lanes, atomic per row
    int colbase = j0 + wcol * 64 + l15;
    int rowbase = i0 + wrow * 64 + lg * 4;
#pragma unroll
    for (int m = 0; m < 4; ++m) {
#pragma unroll
        for (int r = 0; r < 4; ++r) {
            float s = 0.f;
#pragma unroll
            for (int nn = 0; nn < 4; ++nn) {
                if (colbase + nn * 16 < n) s += expf(acc[m][nn][r] * (1.f / TAU_F));
            }
            s += __shfl_xor(s, 1, 64);
            s += __shfl_xor(s, 2, 64);
            s += __shfl_xor(s, 4, 64);
            s += __shfl_xor(s, 8, 64);
            if (l15 == 0) {
                int i = rowbase + m * 16 + r;
                if (i < n) atomicAdd(&R[i], s);
            }
        }
    }
}

__global__ void loss_kernel(const float* __restrict__ R, const float* __restrict__ dvec,
                            float* __restrict__ out_loss, int n) {
    __shared__ float s[1024];
    int t = threadIdx.x;
    float sum = 0.f;
    for (int i = t; i < n; i += 1024) {
        float d   = dvec[i];
        float off = R[i] - d;
        sum += -logf(d / (off + off));
    }
    s[t] = sum;
    __syncthreads();
    for (int o = 512; o > 0; o >>= 1) {
        if (t < o) s[t] += s[t + o];
        __syncthreads();
    }
    if (t == 0) *out_loss = s[0] / n;
}

// ---------------------------------------------------------------------------
extern "C" void kernel_launch(void* const* d_in, const int* in_sizes, int n_in,
                              void* d_out, int out_size, void* d_ws, size_t ws_size,
                              hipStream_t stream) {
    const float* x   = (const float*)d_in[0];
    const int*   src = (const int*)d_in[1];
    const int*   dst = (const int*)d_in[2];
    const float* W0  = (const float*)d_in[3];
    const float* a0s = (const float*)d_in[4];
    const float* a0d = (const float*)d_in[5];
    const float* W1  = (const float*)d_in[6];
    const float* a1s = (const float*)d_in[7];
    const float* a1d = (const float*)d_in[8];
    const float* W2  = (const float*)d_in[9];
    const float* a2s = (const float*)d_in[10];
    const float* a2d = (const float*)d_in[11];
    const float* Wout= (const float*)d_in[12];
    const float* aos = (const float*)d_in[13];
    const float* aod = (const float*)d_in[14];

    int N = in_sizes[0] / NN_F_IN;
    int E = in_sizes[1];
    int Npad = ((N + 127) / 128) * 128;
    float* out = (float*)d_out;

    char*  ws  = (char*)d_ws;
    size_t off = 0;
    auto alloc = [&](size_t bytes) -> void* {
        void* p = ws + off;
        off += bytes;
        off = (off + 255) & ~(size_t)255;
        return p;
    };
    float* Bh     = (float*)alloc((size_t)N * NN_HEADS * NN_NCLASS * 4);  // 320 cols scratch
    float* Bl     = (float*)alloc((size_t)N * NN_HID * 4);
    float* Bc     = (float*)alloc((size_t)N * NN_HID * 4);
    float* es     = (float*)alloc((size_t)N * NN_HEADS * 4);
    float* ed     = (float*)alloc((size_t)N * NN_HEADS * 4);
    float* Rrow   = (float*)alloc((size_t)N * 4);
    float* dvec   = (float*)alloc((size_t)N * 4);
    int*   counts = (int*)alloc((size_t)N * 4);
    int*   rs     = (int*)alloc((size_t)(N + 1) * 4);
    int*   cursor = (int*)alloc((size_t)N * 4);
    int*   csr    = (int*)alloc((size_t)E * 4);
    short* znb    = (short*)alloc((size_t)Npad * NN_HID * 2);

    // ---- CSR build (used by all 4 GAT layers)
    hipMemsetAsync(counts, 0, (size_t)N * 4, stream);
    count_kernel<<<(E + 255) / 256, 256, 0, stream>>>(dst, counts, E);
    scan_kernel<<<1, 1024, 0, stream>>>(counts, rs, N);
    cursor_init<<<(N + 255) / 256, 256, 0, stream>>>(rs, cursor, N);
    scatter_kernel<<<(E + 255) / 256, 256, 0, stream>>>(src, dst, cursor, csr, E);

    int fcGrid = (N + 7) / 8;
    int atGrid = (N * NN_HEADS + 255) / 256;

    // ---- layer 0: x -> Bl
    fc_kernel<<<fcGrid, NN_HID, 0, stream>>>(x, W0, Bh, N, NN_F_IN, NN_HID);
    attn_kernel<<<atGrid, 256, 0, stream>>>(Bh, a0s, a0d, es, ed, N, NN_FH);
    gather_hidden<<<N, 256, 0, stream>>>(Bh, es, ed, csr, rs, nullptr, Bl, N, -1.f);

    // ---- layer 1: Bl -> Bc  (beta = 0.5/3)
    fc_kernel<<<fcGrid, NN_HID, 0, stream>>>(Bl, W1, Bh, N, NN_HID, NN_HID);
    attn_kernel<<<atGrid, 256, 0, stream>>>(Bh, a1s, a1d, es, ed, N, NN_FH);
    gather_hidden<<<N, 256, 0, stream>>>(Bh, es, ed, csr, rs, Bl, Bc, N, LAMDA_F / 3.f);

    // ---- layer 2: Bc -> Bl  (beta = 0.5/4), then bind_loss on Bl
    fc_kernel<<<fcGrid, NN_HID, 0, stream>>>(Bc, W2, Bh, N, NN_HID, NN_HID);
    attn_kernel<<<atGrid, 256, 0, stream>>>(Bh, a2s, a2d, es, ed, N, NN_FH);
    gather_hidden<<<N, 256, 0, stream>>>(Bh, es, ed, csr, rs, Bc, Bl, N, LAMDA_F / 4.f);

    // ---- bind_loss(Bl): zn(bf16) in znb, rowsums in Rrow, loss -> out[N*NCLASS]
    rownorm_kernel<<<N, 256, 0, stream>>>(Bl, znb, dvec, N);
    hipMemsetAsync(znb + (size_t)N * NN_HID, 0, (size_t)(Npad - N) * NN_HID * 2, stream);
    hipMemsetAsync(Rrow, 0, (size_t)N * 4, stream);
    dim3 gg(Npad / 128, Npad / 128);
    gram_mfma<<<gg, 256, 0, stream>>>(znb, Rrow, N);
    loss_kernel<<<1, 1024, 0, stream>>>(Rrow, dvec, out + (size_t)N * NN_NCLASS, N);

    // ---- output layer: Bl -> logits (overwrites Bh after gram is done)
    fc_kernel<<<fcGrid, NN_HEADS * NN_NCLASS, 0, stream>>>(Bl, Wout, Bh, N, NN_HID, NN_HEADS * NN_NCLASS);
    attn_kernel<<<atGrid, 256, 0, stream>>>(Bh, aos, aod, es, ed, N, NN_NCLASS);
    gather_final<<<N, NN_HEADS * NN_NCLASS, 0, stream>>>(Bh, es, ed, csr, rs, out, N);
}

// Round 3
// 668.058 us; speedup vs baseline: 2.0617x; 1.3974x over previous
//
#include <hip/hip_runtime.h>
#include <hip/hip_bf16.h>
#include <math.h>

#define NN_F_IN   512
#define NN_HID    256
#define NN_HEADS  8
#define NN_FH     32
#define NN_NCLASS 40
#define TAU_F     0.5f
#define LAMDA_F   0.5f

typedef __attribute__((ext_vector_type(8))) short bf16x8;
typedef __attribute__((ext_vector_type(4))) float f32x4;

static __device__ __forceinline__ float lrelu02(float x) { return x >= 0.f ? x : 0.2f * x; }
static __device__ __forceinline__ float elu1(float x)    { return x > 0.f ? x : expm1f(x); }
static __device__ __forceinline__ float b2f(unsigned short u) {
    unsigned int x = ((unsigned int)u) << 16;
    return __uint_as_float(x);
}
static __device__ __forceinline__ unsigned short f2b(float f) {
    __hip_bfloat16 hb = __float2bfloat16(f);
    return *reinterpret_cast<unsigned short*>(&hb);
}

// ---------------------------------------------------------------------------
// Dense: H[n][o] = sum_f X[n][f] * W[f][o].  bf16 output.
// ---------------------------------------------------------------------------
__global__ void fc_kernel(const float* __restrict__ X, const float* __restrict__ W,
                          unsigned short* __restrict__ H, int n, int fin, int outdim) {
    __shared__ __align__(16) float xs[8 * 512];
    int n0 = blockIdx.x * 8;
    int o  = threadIdx.x;
    int total = 8 * fin;
    for (int idx = threadIdx.x; idx < total; idx += blockDim.x) {
        int nb = idx / fin, f = idx - nb * fin;
        int nn = n0 + nb;
        xs[nb * fin + f] = (nn < n) ? X[(size_t)nn * fin + f] : 0.f;
    }
    __syncthreads();
    float acc[8] = {0.f, 0.f, 0.f, 0.f, 0.f, 0.f, 0.f, 0.f};
    for (int f4 = 0; f4 < fin; f4 += 4) {
        float4 xv[8];
#pragma unroll
        for (int nb = 0; nb < 8; ++nb) xv[nb] = *(const float4*)&xs[nb * fin + f4];
#pragma unroll
        for (int j = 0; j < 4; ++j) {
            float w = W[(size_t)(f4 + j) * outdim + o];
#pragma unroll
            for (int nb = 0; nb < 8; ++nb) {
                float xj = (j == 0) ? xv[nb].x : (j == 1) ? xv[nb].y : (j == 2) ? xv[nb].z : xv[nb].w;
                acc[nb] += xj * w;
            }
        }
    }
#pragma unroll
    for (int nb = 0; nb < 8; ++nb) {
        int nn = n0 + nb;
        if (nn < n) H[(size_t)nn * outdim + o] = f2b(acc[nb]);
    }
}

// ---------------------------------------------------------------------------
// es/ed dot products, Hm is bf16 now.
// ---------------------------------------------------------------------------
__global__ void attn_kernel(const unsigned short* __restrict__ Hm, const float* __restrict__ As,
                            const float* __restrict__ Ad, float* __restrict__ es,
                            float* __restrict__ ed, int n, int df) {
    int idx = blockIdx.x * blockDim.x + threadIdx.x;
    if (idx >= n * NN_HEADS) return;
    int nn = idx / NN_HEADS, hh = idx - nn * NN_HEADS;
    const unsigned short* hp = Hm + (size_t)nn * NN_HEADS * df + hh * df;
    const float* ap = As + hh * df;
    const float* bp = Ad + hh * df;
    float s1 = 0.f, s2 = 0.f;
    for (int d = 0; d < df; d += 4) {
        ushort4 hv = *(const ushort4*)(hp + d);
        float4 av = *(const float4*)(ap + d);
        float4 bv = *(const float4*)(bp + d);
        float h0 = b2f(hv.x), h1 = b2f(hv.y), h2 = b2f(hv.z), h3 = b2f(hv.w);
        s1 += h0 * av.x + h1 * av.y + h2 * av.z + h3 * av.w;
        s2 += h0 * bv.x + h1 * bv.y + h2 * bv.z + h3 * bv.w;
    }
    es[idx] = s1;
    ed[idx] = s2;
}

// ---------------------------------------------------------------------------
// CSR build
// ---------------------------------------------------------------------------
__global__ void count_kernel(const int* __restrict__ dst, int* __restrict__ counts, int E) {
    int e = blockIdx.x * blockDim.x + threadIdx.x;
    if (e < E) atomicAdd(&counts[dst[e]], 1);
}

__global__ void scan_kernel(const int* __restrict__ counts, int* __restrict__ row_start, int n) {
    __shared__ int s[1024];
    int t  = threadIdx.x;
    int ch = (n + 1023) / 1024;
    int lo = t * ch;
    int sum = 0;
    for (int j = 0; j < ch; ++j) {
        int i = lo + j;
        if (i < n) sum += counts[i];
    }
    s[t] = sum;
    __syncthreads();
    for (int off = 1; off < 1024; off <<= 1) {
        int v = 0;
        if (t >= off) v = s[t - off];
        __syncthreads();
        s[t] += v;
        __syncthreads();
    }
    int run = (t == 0) ? 0 : s[t - 1];
    for (int j = 0; j < ch; ++j) {
        int i = lo + j;
        if (i < n) {
            row_start[i] = run;
            run += counts[i];
        }
    }
    if (t == 1023) row_start[n] = s[1023];
}

__global__ void cursor_init(const int* __restrict__ rs, int* __restrict__ cursor, int n) {
    int i = blockIdx.x * blockDim.x + threadIdx.x;
    if (i < n) cursor[i] = rs[i];
}

__global__ void scatter_kernel(const int* __restrict__ src, const int* __restrict__ dst,
                               int* __restrict__ cursor, int* __restrict__ csr_src, int E) {
    int e = blockIdx.x * blockDim.x + threadIdx.x;
    if (e < E) {
        int d   = dst[e];
        int pos = atomicAdd(&cursor[d], 1);
        csr_src[pos] = src[e];
    }
}

// ---------------------------------------------------------------------------
// Hidden-layer gather: 1 wave per node, 4 nodes per 256-thread block.
// Phase 1: wave-parallel z (lane = 8*edge_slot + head). Phase 2: 4-wide
// unrolled aggregation, lane owns features [lane*4, lane*4+3], head=lane>>3.
// ---------------------------------------------------------------------------
__global__ __launch_bounds__(256) void gather_hidden(
    const unsigned short* __restrict__ Hm, const float* __restrict__ es,
    const float* __restrict__ ed, const int* __restrict__ csr_src,
    const int* __restrict__ row_start, const float* __restrict__ last,
    float* __restrict__ out, int n, float beta) {
    int lane = threadIdx.x & 63;
    int nn   = blockIdx.x * 4 + (threadIdx.x >> 6);
    if (nn >= n) return;
    int s0 = row_start[nn], s1 = row_start[nn + 1];

    // phase 1: z per head
    int h1 = lane & 7;
    float edv = ed[nn * NN_HEADS + h1];
    float zp = 0.f;
    for (int e = s0 + (lane >> 3); e < s1; e += 8) {
        int sv = csr_src[e];
        zp += expf(lrelu02(es[sv * NN_HEADS + h1] + edv));
    }
    zp += __shfl_xor(zp, 8, 64);
    zp += __shfl_xor(zp, 16, 64);
    zp += __shfl_xor(zp, 32, 64);
    // lane l now holds z[l&7]
    int h2 = lane >> 3;
    float zinv = 1.f / __shfl(zp, h2, 64);
    float edh  = __shfl(edv, h2, 64);

    // phase 2: aggregate, 4 edges per chunk with all loads issued up front
    float a0 = 0.f, a1 = 0.f, a2 = 0.f, a3 = 0.f;
    for (int e = s0; e < s1; e += 4) {
        int c = s1 - e;
        int sv0 = csr_src[e];
        int sv1 = csr_src[c > 1 ? e + 1 : e];
        int sv2 = csr_src[c > 2 ? e + 2 : e];
        int sv3 = csr_src[c > 3 ? e + 3 : e];
        float q0 = es[sv0 * NN_HEADS + h2];
        float q1 = es[sv1 * NN_HEADS + h2];
        float q2 = es[sv2 * NN_HEADS + h2];
        float q3 = es[sv3 * NN_HEADS + h2];
        ushort4 r0 = *(const ushort4*)&Hm[(size_t)sv0 * NN_HID + lane * 4];
        ushort4 r1 = *(const ushort4*)&Hm[(size_t)sv1 * NN_HID + lane * 4];
        ushort4 r2 = *(const ushort4*)&Hm[(size_t)sv2 * NN_HID + lane * 4];
        ushort4 r3 = *(const ushort4*)&Hm[(size_t)sv3 * NN_HID + lane * 4];
        float w0 = expf(lrelu02(q0 + edh)) * zinv;
        a0 += w0 * b2f(r0.x); a1 += w0 * b2f(r0.y); a2 += w0 * b2f(r0.z); a3 += w0 * b2f(r0.w);
        if (c > 1) {
            float w1 = expf(lrelu02(q1 + edh)) * zinv;
            a0 += w1 * b2f(r1.x); a1 += w1 * b2f(r1.y); a2 += w1 * b2f(r1.z); a3 += w1 * b2f(r1.w);
        }
        if (c > 2) {
            float w2 = expf(lrelu02(q2 + edh)) * zinv;
            a0 += w2 * b2f(r2.x); a1 += w2 * b2f(r2.y); a2 += w2 * b2f(r2.z); a3 += w2 * b2f(r2.w);
        }
        if (c > 3) {
            float w3 = expf(lrelu02(q3 + edh)) * zinv;
            a0 += w3 * b2f(r3.x); a1 += w3 * b2f(r3.y); a2 += w3 * b2f(r3.z); a3 += w3 * b2f(r3.w);
        }
    }
    float4 v;
    v.x = elu1(a0); v.y = elu1(a1); v.z = elu1(a2); v.w = elu1(a3);
    if (beta >= 0.f) {
        float4 lv = *(const float4*)&last[(size_t)nn * NN_HID + lane * 4];
        v.x = beta * lv.x + (1.f - beta) * v.x;
        v.y = beta * lv.y + (1.f - beta) * v.y;
        v.z = beta * lv.z + (1.f - beta) * v.z;
        v.w = beta * lv.w + (1.f - beta) * v.w;
    }
    *(float4*)&out[(size_t)nn * NN_HID + lane * 4] = v;
}

// ---------------------------------------------------------------------------
// Final layer: aggregate [N,H,C] (bf16), mean heads, log_softmax -> d_out
// ---------------------------------------------------------------------------
__global__ void gather_final(const unsigned short* __restrict__ Hm, const float* __restrict__ es,
                             const float* __restrict__ ed, const int* __restrict__ csr_src,
                             const int* __restrict__ row_start, float* __restrict__ dout, int n) {
    int nn = blockIdx.x;
    __shared__ float edn[NN_HEADS];
    __shared__ float zs[NN_HEADS];
    __shared__ float zinv[NN_HEADS];
    __shared__ float accs[NN_HEADS * NN_NCLASS];
    int t = threadIdx.x;  // 0..319
    if (t < NN_HEADS) {
        edn[t] = ed[nn * NN_HEADS + t];
        zs[t]  = 0.f;
    }
    __syncthreads();
    int s0 = row_start[nn], s1 = row_start[nn + 1];
    int work = (s1 - s0) * NN_HEADS;
    for (int idx = t; idx < work; idx += blockDim.x) {
        int e  = s0 + (idx >> 3);
        int hh = idx & 7;
        int sv = csr_src[e];
        atomicAdd(&zs[hh], expf(lrelu02(es[sv * NN_HEADS + hh] + edn[hh])));
    }
    __syncthreads();
    if (t < NN_HEADS) zinv[t] = 1.f / zs[t];
    __syncthreads();
    int   hh  = t / NN_NCLASS;
    float edh = edn[hh];
    float zi  = zinv[hh];
    float acc = 0.f;
    const int LD = NN_HEADS * NN_NCLASS;
    for (int e = s0; e < s1; e += 4) {
        int c = s1 - e;
        int sv0 = csr_src[e];
        int sv1 = csr_src[c > 1 ? e + 1 : e];
        int sv2 = csr_src[c > 2 ? e + 2 : e];
        int sv3 = csr_src[c > 3 ? e + 3 : e];
        float q0 = es[sv0 * NN_HEADS + hh];
        float q1 = es[sv1 * NN_HEADS + hh];
        float q2 = es[sv2 * NN_HEADS + hh];
        float q3 = es[sv3 * NN_HEADS + hh];
        float v0 = b2f(Hm[(size_t)sv0 * LD + t]);
        float v1 = b2f(Hm[(size_t)sv1 * LD + t]);
        float v2 = b2f(Hm[(size_t)sv2 * LD + t]);
        float v3 = b2f(Hm[(size_t)sv3 * LD + t]);
        acc += expf(lrelu02(q0 + edh)) * zi * v0;
        if (c > 1) acc += expf(lrelu02(q1 + edh)) * zi * v1;
        if (c > 2) acc += expf(lrelu02(q2 + edh)) * zi * v2;
        if (c > 3) acc += expf(lrelu02(q3 + edh)) * zi * v3;
    }
    accs[t] = acc;
    __syncthreads();
    if (t < 64) {
        float v = -INFINITY;
        if (t < NN_NCLASS) {
            float sacc = 0.f;
#pragma unroll
            for (int h2 = 0; h2 < NN_HEADS; ++h2) sacc += accs[h2 * NN_NCLASS + t];
            v = sacc * (1.f / NN_HEADS);
        }
        float mx = v;
#pragma unroll
        for (int o = 1; o < 64; o <<= 1) mx = fmaxf(mx, __shfl_xor(mx, o, 64));
        float ex = (t < NN_NCLASS) ? expf(v - mx) : 0.f;
        float se = ex;
#pragma unroll
        for (int o = 1; o < 64; o <<= 1) se += __shfl_xor(se, o, 64);
        if (t < NN_NCLASS) dout[(size_t)nn * NN_NCLASS + t] = (v - mx) - logf(se);
    }
}

// ---------------------------------------------------------------------------
// Row-normalize + bf16 cast + analytic diagonal d_i = exp(||zn_i||^2 / tau)
// ---------------------------------------------------------------------------
__global__ void rownorm_kernel(const float* __restrict__ z, short* __restrict__ znb,
                               float* __restrict__ dvec, int n) {
    int nn = blockIdx.x;
    int t  = threadIdx.x;  // 256
    float v  = z[(size_t)nn * NN_HID + t];
    float sq = v * v;
#pragma unroll
    for (int o = 1; o < 64; o <<= 1) sq += __shfl_xor(sq, o, 64);
    __shared__ float ws[4];
    if ((t & 63) == 0) ws[t >> 6] = sq;
    __syncthreads();
    float s = ws[0] + ws[1] + ws[2] + ws[3];
    float m = fmaxf(sqrtf(s), 1e-12f);
    znb[(size_t)nn * NN_HID + t] = (short)f2b(v / m);
    if (t == 0) dvec[nn] = expf((s / (m * m)) * (1.f / TAU_F));
}

// ---------------------------------------------------------------------------
// Symmetric gram rowsums: upper-triangle 128x128 blocks only.
// Off-diagonal block (bi,bj): rowsum -> R[i], colsum -> R[j] (S symmetric).
// 4 waves 2x2, wave = 64x64 = 4x4 frags of mfma_f32_16x16x32_bf16.
// Register double-buffer across K-steps; bijective XCD swizzle on block id.
// ---------------------------------------------------------------------------
__global__ __launch_bounds__(256) void gram_mfma(const short* __restrict__ znb,
                                                 float* __restrict__ R, int n,
                                                 int T, int nwg) {
    // XCD swizzle: contiguous triangle rows per XCD
    int b = blockIdx.x;
    int q = nwg >> 3, rr8 = nwg & 7, xc = b & 7, oo = b >> 3;
    int tile = (xc < rr8 ? xc * (q + 1) : rr8 * (q + 1) + (xc - rr8) * q) + oo;
    // triangular decode (row-major upper triangle incl. diagonal)
    int bi = 0, rem = tile;
    while (rem >= T - bi) { rem -= T - bi; ++bi; }
    int bj = bi + rem;
    int i0 = bi * 128, j0 = bj * 128;

    int t    = threadIdx.x;
    int lane = t & 63;
    int wid  = t >> 6;
    int wrow = wid >> 1, wcol = wid & 1;
    int l15  = lane & 15, lg = lane >> 4;

    const short* Ab = znb + (size_t)(i0 + wrow * 64 + l15) * NN_HID + lg * 8;
    const short* Bb = znb + (size_t)(j0 + wcol * 64 + l15) * NN_HID + lg * 8;

    f32x4 acc[4][4];
#pragma unroll
    for (int m = 0; m < 4; ++m)
#pragma unroll
        for (int nn = 0; nn < 4; ++nn)
#pragma unroll
            for (int r = 0; r < 4; ++r) acc[m][nn][r] = 0.f;

    bf16x8 aP[4], bP[4], aQ[4], bQ[4];
#pragma unroll
    for (int m = 0; m < 4; ++m) {
        aP[m] = *(const bf16x8*)(Ab + (size_t)m * 16 * NN_HID);
        bP[m] = *(const bf16x8*)(Bb + (size_t)m * 16 * NN_HID);
    }
#pragma unroll
    for (int s = 0; s < 8; ++s) {
        const bf16x8* ac = (s & 1) ? aQ : aP;
        const bf16x8* bc = (s & 1) ? bQ : bP;
        bf16x8* an = (s & 1) ? aP : aQ;
        bf16x8* bn = (s & 1) ? bP : bQ;
        if (s < 7) {
            int kk = (s + 1) * 32;
#pragma unroll
            for (int m = 0; m < 4; ++m) {
                an[m] = *(const bf16x8*)(Ab + (size_t)m * 16 * NN_HID + kk);
                bn[m] = *(const bf16x8*)(Bb + (size_t)m * 16 * NN_HID + kk);
            }
        }
#pragma unroll
        for (int m = 0; m < 4; ++m)
#pragma unroll
            for (int nn = 0; nn < 4; ++nn)
                acc[m][nn] = __builtin_amdgcn_mfma_f32_16x16x32_bf16(ac[m], bc[nn], acc[m][nn], 0, 0, 0);
    }

    // epilogue: s = exp(2*acc) masked to (i<n && j<n); rowsums always,
    // colsums when off-diagonal block.
    bool diag = (bi == bj);
    float rowpart[4][4];
    float colpart[4] = {0.f, 0.f, 0.f, 0.f};
#pragma unroll
    for (int m = 0; m < 4; ++m)
#pragma unroll
        for (int r = 0; r < 4; ++r) rowpart[m][r] = 0.f;

#pragma unroll
    for (int m = 0; m < 4; ++m) {
        int gi_b = i0 + wrow * 64 + m * 16 + lg * 4;
#pragma unroll
        for (int nn = 0; nn < 4; ++nn) {
            int gj = j0 + wcol * 64 + nn * 16 + l15;
            bool jok = (gj < n);
#pragma unroll
            for (int r = 0; r < 4; ++r) {
                float sv = (jok && (gi_b + r) < n) ? expf(acc[m][nn][r] * (1.f / TAU_F)) : 0.f;
                rowpart[m][r] += sv;
                colpart[nn] += sv;
            }
        }
    }
    // rowsums: reduce over 16 col-lanes
#pragma unroll
    for (int m = 0; m < 4; ++m) {
#pragma unroll
        for (int r = 0; r < 4; ++r) {
            float v = rowpart[m][r];
            v += __shfl_xor(v, 1, 64);
            v += __shfl_xor(v, 2, 64);
            v += __shfl_xor(v, 4, 64);
            v += __shfl_xor(v, 8, 64);
            if (l15 == 0) {
                int gi = i0 + wrow * 64 + m * 16 + lg * 4 + r;
                if (gi < n) atomicAdd(&R[gi], v);
            }
        }
    }
    // colsums (symmetry): reduce over 4 row-groups (lg)
    if (!diag) {
#pragma unroll
        for (int nn = 0; nn < 4; ++nn) {
            float v = colpart[nn];
            v += __shfl_xor(v, 16, 64);
            v += __shfl_xor(v, 32, 64);
            if (lg == 0) {
                int gj = j0 + wcol * 64 + nn * 16 + l15;
                if (gj < n) atomicAdd(&R[gj], v);
            }
        }
    }
}

__global__ void loss_kernel(const float* __restrict__ R, const float* __restrict__ dvec,
                            float* __restrict__ out_loss, int n) {
    __shared__ float s[1024];
    int t = threadIdx.x;
    float sum = 0.f;
    for (int i = t; i < n; i += 1024) {
        float d   = dvec[i];
        float off = R[i] - d;
        sum += -logf(d / (off + off));
    }
    s[t] = sum;
    __syncthreads();
    for (int o = 512; o > 0; o >>= 1) {
        if (t < o) s[t] += s[t + o];
        __syncthreads();
    }
    if (t == 0) *out_loss = s[0] / n;
}

// ---------------------------------------------------------------------------
extern "C" void kernel_launch(void* const* d_in, const int* in_sizes, int n_in,
                              void* d_out, int out_size, void* d_ws, size_t ws_size,
                              hipStream_t stream) {
    const float* x   = (const float*)d_in[0];
    const int*   src = (const int*)d_in[1];
    const int*   dst = (const int*)d_in[2];
    const float* W0  = (const float*)d_in[3];
    const float* a0s = (const float*)d_in[4];
    const float* a0d = (const float*)d_in[5];
    const float* W1  = (const float*)d_in[6];
    const float* a1s = (const float*)d_in[7];
    const float* a1d = (const float*)d_in[8];
    const float* W2  = (const float*)d_in[9];
    const float* a2s = (const float*)d_in[10];
    const float* a2d = (const float*)d_in[11];
    const float* Wout= (const float*)d_in[12];
    const float* aos = (const float*)d_in[13];
    const float* aod = (const float*)d_in[14];

    int N = in_sizes[0] / NN_F_IN;
    int E = in_sizes[1];
    int Npad = ((N + 127) / 128) * 128;
    int T = Npad / 128;
    int nwg = T * (T + 1) / 2;
    float* out = (float*)d_out;

    char*  ws  = (char*)d_ws;
    size_t off = 0;
    auto alloc = [&](size_t bytes) -> void* {
        void* p = ws + off;
        off += bytes;
        off = (off + 255) & ~(size_t)255;
        return p;
    };
    unsigned short* Hb = (unsigned short*)alloc((size_t)N * NN_HEADS * NN_NCLASS * 2);  // bf16, 320 cols max
    float* Bl     = (float*)alloc((size_t)N * NN_HID * 4);
    float* Bc     = (float*)alloc((size_t)N * NN_HID * 4);
    float* es     = (float*)alloc((size_t)N * NN_HEADS * 4);
    float* ed     = (float*)alloc((size_t)N * NN_HEADS * 4);
    float* Rrow   = (float*)alloc((size_t)N * 4);
    float* dvec   = (float*)alloc((size_t)N * 4);
    int*   counts = (int*)alloc((size_t)N * 4);
    int*   rs     = (int*)alloc((size_t)(N + 1) * 4);
    int*   cursor = (int*)alloc((size_t)N * 4);
    int*   csr    = (int*)alloc((size_t)E * 4);
    short* znb    = (short*)alloc((size_t)Npad * NN_HID * 2);

    // ---- CSR build
    hipMemsetAsync(counts, 0, (size_t)N * 4, stream);
    count_kernel<<<(E + 255) / 256, 256, 0, stream>>>(dst, counts, E);
    scan_kernel<<<1, 1024, 0, stream>>>(counts, rs, N);
    cursor_init<<<(N + 255) / 256, 256, 0, stream>>>(rs, cursor, N);
    scatter_kernel<<<(E + 255) / 256, 256, 0, stream>>>(src, dst, cursor, csr, E);

    int fcGrid = (N + 7) / 8;
    int atGrid = (N * NN_HEADS + 255) / 256;
    int ghGrid = (N + 3) / 4;

    // ---- layer 0: x -> Bl
    fc_kernel<<<fcGrid, NN_HID, 0, stream>>>(x, W0, Hb, N, NN_F_IN, NN_HID);
    attn_kernel<<<atGrid, 256, 0, stream>>>(Hb, a0s, a0d, es, ed, N, NN_FH);
    gather_hidden<<<ghGrid, 256, 0, stream>>>(Hb, es, ed, csr, rs, nullptr, Bl, N, -1.f);

    // ---- layer 1: Bl -> Bc  (beta = 0.5/3)
    fc_kernel<<<fcGrid, NN_HID, 0, stream>>>(Bl, W1, Hb, N, NN_HID, NN_HID);
    attn_kernel<<<atGrid, 256, 0, stream>>>(Hb, a1s, a1d, es, ed, N, NN_FH);
    gather_hidden<<<ghGrid, 256, 0, stream>>>(Hb, es, ed, csr, rs, Bl, Bc, N, LAMDA_F / 3.f);

    // ---- layer 2: Bc -> Bl  (beta = 0.5/4)
    fc_kernel<<<fcGrid, NN_HID, 0, stream>>>(Bc, W2, Hb, N, NN_HID, NN_HID);
    attn_kernel<<<atGrid, 256, 0, stream>>>(Hb, a2s, a2d, es, ed, N, NN_FH);
    gather_hidden<<<ghGrid, 256, 0, stream>>>(Hb, es, ed, csr, rs, Bc, Bl, N, LAMDA_F / 4.f);

    // ---- bind_loss(Bl)
    rownorm_kernel<<<N, 256, 0, stream>>>(Bl, znb, dvec, N);
    hipMemsetAsync(znb + (size_t)N * NN_HID, 0, (size_t)(Npad - N) * NN_HID * 2, stream);
    hipMemsetAsync(Rrow, 0, (size_t)N * 4, stream);
    gram_mfma<<<nwg, 256, 0, stream>>>(znb, Rrow, N, T, nwg);
    loss_kernel<<<1, 1024, 0, stream>>>(Rrow, dvec, out + (size_t)N * NN_NCLASS, N);

    // ---- output layer
    fc_kernel<<<fcGrid, NN_HEADS * NN_NCLASS, 0, stream>>>(Bl, Wout, Hb, N, NN_HID, NN_HEADS * NN_NCLASS);
    attn_kernel<<<atGrid, 256, 0, stream>>>(Hb, aos, aod, es, ed, N, NN_NCLASS);
    gather_final<<<N, NN_HEADS * NN_NCLASS, 0, stream>>>(Hb, es, ed, csr, rs, out, N);
}